// Round 3
// baseline (162539.880 us; speedup 1.0000x reference)
//
#include <hip/hip_runtime.h>
#include <stdint.h>
#include <math.h>

#define HID   1024
#define CHARD 512
#define NC    50257
#define TLEN  2048
#define NBS   1571          // screen blocks: 32 rows each -> 50272 >= 50257
#define NBH   1571          // fallback head blocks
#define SQ    4064.0f       // 127 / 0.03125
#define INVSQ (1.0f/4064.0f)
#define QERR  (0.5f/4064.0f)

typedef unsigned long long ull;
typedef unsigned char u8;
typedef float f32x4 __attribute__((ext_vector_type(4)));

__device__ __forceinline__ unsigned ford(float f) {
    unsigned b = __float_as_uint(f);
    return (b & 0x80000000u) ? ~b : (b | 0x80000000u);
}
__device__ __forceinline__ float unford(unsigned u) {
    return __uint_as_float((u & 0x80000000u) ? (u & 0x7FFFFFFFu) : ~u);
}
__device__ __forceinline__ ull packkv(float v, unsigned j) {
    return ((ull)ford(v) << 32) | (ull)(0xFFFFFFFFu - j);
}
__device__ __forceinline__ ull umaxu(ull a, ull b) { return a > b ? a : b; }
__device__ __forceinline__ ull shflx_ull(ull v, int m) {
    unsigned lo = (unsigned)v, hi = (unsigned)(v >> 32);
    lo = __shfl_xor(lo, m);
    hi = __shfl_xor(hi, m);
    return ((ull)hi << 32) | lo;
}

// ================= init: hh[0] = inputs, c = 0 =================
__global__ __launch_bounds__(256) void k_init(const float* __restrict__ inputs,
                                              float* __restrict__ hh,
                                              float* __restrict__ c)
{
    int tid = blockIdx.x * 256 + threadIdx.x;
    if (tid < HID) { hh[tid] = inputs[tid]; c[tid] = 0.f; }
}

// ================= quantize W_head -> int8 (scale SQ) =================
__global__ __launch_bounds__(256) void k_quant(const float* __restrict__ W,
                                               u8* __restrict__ W8)
{
    size_t base = ((size_t)blockIdx.x * 256 + threadIdx.x) * 16;
    if (base >= (size_t)NC * HID) return;
    const float4* src = (const float4*)(W + base);
    uint out[4];
    #pragma unroll
    for (int g = 0; g < 4; ++g) {
        float4 w = src[g];
        int a0 = __float2int_rn(w.x * SQ) & 255;
        int a1 = __float2int_rn(w.y * SQ) & 255;
        int a2 = __float2int_rn(w.z * SQ) & 255;
        int a3 = __float2int_rn(w.w * SQ) & 255;
        out[g] = (uint)(a0 | (a1 << 8) | (a2 << 16) | (a3 << 24));
    }
    *(uint4*)(W8 + base) = make_uint4(out[0], out[1], out[2], out[3]);
}

// ================= resolve exact argmax of previous step =================
// Candidates: screen-blocks with blockmax >= m~ - 2E; within them rows with
// abuf[j] >= m~ - 2E. True argmax provably in candidate set. Exact fp32
// recompute of candidates -> exact argmax (ties -> lowest index).
__device__ __forceinline__ unsigned resolve_char(const float4* hs4,
                                                 const ull* __restrict__ blockmax,
                                                 const float* __restrict__ abuf,
                                                 const float* __restrict__ W_head,
                                                 const float* __restrict__ b_head,
                                                 float Sh, ull* red4, int tid)
{
    const int wave = tid >> 6;
    const int lane = tid & 63;

    // global screen max
    ull pm = 0ull;
    for (int i = tid; i < NBS; i += 256) pm = umaxu(pm, blockmax[i]);
    #pragma unroll
    for (int off = 32; off > 0; off >>= 1) pm = umaxu(pm, shflx_ull(pm, off));
    if (lane == 0) red4[wave] = pm;
    __syncthreads();
    pm = umaxu(umaxu(red4[0], red4[1]), umaxu(red4[2], red4[3]));
    const float mtil = unford((unsigned)(pm >> 32));
    const float E = QERR * Sh * 1.02f + 1e-4f;
    const float thresh = mtil - 2.0f * E;
    const ull pkth = ((ull)ford(thresh)) << 32;
    __syncthreads();

    // wave-parallel candidate refinement
    ull best = 0ull;
    for (int i = wave; i < NBS; i += 4) {
        if (blockmax[i] >= pkth) {
            const int jbase = i * 32;
            for (int rr = 0; rr < 32; ++rr) {
                const int j = jbase + rr;
                if (j >= NC) break;
                if (abuf[j] >= thresh) {
                    const float4* wr = (const float4*)(W_head + (size_t)j * HID);
                    float a = 0.f;
                    #pragma unroll
                    for (int m = 0; m < 4; ++m) {
                        float4 w = wr[m * 64 + lane], v = hs4[m * 64 + lane];
                        a = fmaf(w.x, v.x, a); a = fmaf(w.y, v.y, a);
                        a = fmaf(w.z, v.z, a); a = fmaf(w.w, v.w, a);
                    }
                    #pragma unroll
                    for (int off = 32; off > 0; off >>= 1) a += __shfl_xor(a, off);
                    best = umaxu(best, packkv(a + b_head[j], (unsigned)j));
                }
            }
        }
    }
    if (lane == 0) red4[wave] = best;
    __syncthreads();
    best = umaxu(umaxu(red4[0], red4[1]), umaxu(red4[2], red4[3]));
    unsigned idx = 0xFFFFFFFFu - (unsigned)(best & 0xFFFFFFFFull);
    return idx < NC ? idx : (NC - 1);
}

// ================= LSTM step (+ exact argmax of prev step) =================
__global__ __launch_bounds__(256) void k_lstm(const float* __restrict__ W_ih,
                                              const float* __restrict__ W_hh,
                                              const float* __restrict__ b_ih,
                                              const float* __restrict__ b_hh,
                                              const float* __restrict__ embed,
                                              const float* __restrict__ W_head,
                                              const float* __restrict__ b_head,
                                              const ull* __restrict__ blockmax,
                                              const float* __restrict__ abuf,
                                              const float* __restrict__ h_in,
                                              float* __restrict__ h_out,
                                              float* __restrict__ c,
                                              float* __restrict__ chars_out,
                                              const int* __restrict__ startp,
                                              int t)
{
    __shared__ float4 xs4[CHARD / 4];   // 128
    __shared__ float4 hs4[HID / 4];     // 256
    __shared__ ull    red4[4];
    __shared__ float  sred[4];

    const int tid  = threadIdx.x;
    const int wave = tid >> 6;
    const int lane = tid & 63;

    // stage h + sum |h|
    float4 hv = ((const float4*)h_in)[tid];
    hs4[tid] = hv;
    float sa = fabsf(hv.x) + fabsf(hv.y) + fabsf(hv.z) + fabsf(hv.w);
    #pragma unroll
    for (int off = 32; off > 0; off >>= 1) sa += __shfl_xor(sa, off);
    if (lane == 0) sred[wave] = sa;
    __syncthreads();
    const float Sh = sred[0] + sred[1] + sred[2] + sred[3];

    unsigned idx;
    if (t == 0) {
        idx = (unsigned)startp[0];
    } else {
        idx = resolve_char(hs4, blockmax, abuf, W_head, b_head, Sh, red4, tid);
        if (blockIdx.x == 0 && tid == 0) chars_out[t - 1] = (float)idx;
    }

    // stage x = embed[idx]
    const float4* ex = (const float4*)(embed + (size_t)idx * CHARD);
    if (tid < 128) xs4[tid] = ex[tid];
    __syncthreads();

    const int r = blockIdx.x * 4 + wave;   // output element 0..1023

    float acc[4];
    #pragma unroll
    for (int q = 0; q < 4; ++q) {
        const float4* wi = (const float4*)(W_ih + (size_t)(q * HID + r) * CHARD);
        const float4* wh = (const float4*)(W_hh + (size_t)(q * HID + r) * HID);
        float a = 0.f;
        #pragma unroll
        for (int m = 0; m < 2; ++m) {
            float4 w = wi[m * 64 + lane], v = xs4[m * 64 + lane];
            a = fmaf(w.x, v.x, a); a = fmaf(w.y, v.y, a);
            a = fmaf(w.z, v.z, a); a = fmaf(w.w, v.w, a);
        }
        #pragma unroll
        for (int m = 0; m < 4; ++m) {
            float4 w = wh[m * 64 + lane], v = hs4[m * 64 + lane];
            a = fmaf(w.x, v.x, a); a = fmaf(w.y, v.y, a);
            a = fmaf(w.z, v.z, a); a = fmaf(w.w, v.w, a);
        }
        acc[q] = a;
    }
    #pragma unroll
    for (int q = 0; q < 4; ++q) {
        #pragma unroll
        for (int off = 32; off > 0; off >>= 1) acc[q] += __shfl_xor(acc[q], off);
    }

    if (lane == 0) {
        float zi = acc[0] + b_ih[r]           + b_hh[r];
        float zf = acc[1] + b_ih[HID + r]     + b_hh[HID + r];
        float zg = acc[2] + b_ih[2 * HID + r] + b_hh[2 * HID + r];
        float zo = acc[3] + b_ih[3 * HID + r] + b_hh[3 * HID + r];
        float ig = 1.f / (1.f + expf(-zi));
        float fg = 1.f / (1.f + expf(-zf));
        float gg = tanhf(zg);
        float og = 1.f / (1.f + expf(-zo));
        float cn = fg * c[r] + ig * gg;
        c[r] = cn;
        h_out[r] = og * tanhf(cn);
    }
}

// ================= int8 screening head =================
__global__ __launch_bounds__(256) void k_screen(const u8* __restrict__ W8,
                                                const float* __restrict__ b_head,
                                                const float* __restrict__ h_in,
                                                float* __restrict__ abuf,
                                                ull* __restrict__ blockmax)
{
    __shared__ float4 hs4[HID / 4];
    __shared__ ull    wred[4];

    const int tid  = threadIdx.x;
    const int wave = tid >> 6;
    const int lane = tid & 63;

    hs4[tid] = ((const float4*)h_in)[tid];
    __syncthreads();

    const float4 h0 = hs4[lane * 4 + 0];
    const float4 h1 = hs4[lane * 4 + 1];
    const float4 h2 = hs4[lane * 4 + 2];
    const float4 h3 = hs4[lane * 4 + 3];

    const int base = blockIdx.x * 32 + wave * 8;
    ull pm = 0ull;
    #pragma unroll
    for (int rep = 0; rep < 8; ++rep) {
        const int j = base + rep;
        if (j < NC) {
            uint4 q = ((const uint4*)(W8 + (size_t)j * HID))[lane];
            float a = 0.f;
            a = fmaf((float)((int)(q.x << 24) >> 24), h0.x, a);
            a = fmaf((float)((int)(q.x << 16) >> 24), h0.y, a);
            a = fmaf((float)((int)(q.x <<  8) >> 24), h0.z, a);
            a = fmaf((float)((int)(q.x      ) >> 24), h0.w, a);
            a = fmaf((float)((int)(q.y << 24) >> 24), h1.x, a);
            a = fmaf((float)((int)(q.y << 16) >> 24), h1.y, a);
            a = fmaf((float)((int)(q.y <<  8) >> 24), h1.z, a);
            a = fmaf((float)((int)(q.y      ) >> 24), h1.w, a);
            a = fmaf((float)((int)(q.z << 24) >> 24), h2.x, a);
            a = fmaf((float)((int)(q.z << 16) >> 24), h2.y, a);
            a = fmaf((float)((int)(q.z <<  8) >> 24), h2.z, a);
            a = fmaf((float)((int)(q.z      ) >> 24), h2.w, a);
            a = fmaf((float)((int)(q.w << 24) >> 24), h3.x, a);
            a = fmaf((float)((int)(q.w << 16) >> 24), h3.y, a);
            a = fmaf((float)((int)(q.w <<  8) >> 24), h3.z, a);
            a = fmaf((float)((int)(q.w      ) >> 24), h3.w, a);
            #pragma unroll
            for (int off = 32; off > 0; off >>= 1) a += __shfl_xor(a, off);
            const float v = a * INVSQ + b_head[j];
            if (lane == 0) abuf[j] = v;
            pm = umaxu(pm, packkv(v, (unsigned)j));
        }
    }
    if (lane == 0) wred[wave] = pm;
    __syncthreads();
    if (tid == 0)
        blockmax[blockIdx.x] = umaxu(umaxu(wred[0], wred[1]), umaxu(wred[2], wred[3]));
}

// ================= final char (t = TLEN-1) =================
__global__ __launch_bounds__(256) void k_finalc(const float* __restrict__ h_in,
                                                const ull* __restrict__ blockmax,
                                                const float* __restrict__ abuf,
                                                const float* __restrict__ W_head,
                                                const float* __restrict__ b_head,
                                                float* __restrict__ chars_out)
{
    __shared__ float4 hs4[HID / 4];
    __shared__ ull    red4[4];
    __shared__ float  sred[4];
    const int tid  = threadIdx.x;
    const int wave = tid >> 6;
    const int lane = tid & 63;

    float4 hv = ((const float4*)h_in)[tid];
    hs4[tid] = hv;
    float sa = fabsf(hv.x) + fabsf(hv.y) + fabsf(hv.z) + fabsf(hv.w);
    #pragma unroll
    for (int off = 32; off > 0; off >>= 1) sa += __shfl_xor(sa, off);
    if (lane == 0) sred[wave] = sa;
    __syncthreads();
    const float Sh = sred[0] + sred[1] + sred[2] + sred[3];
    unsigned idx = resolve_char(hs4, blockmax, abuf, W_head, b_head, Sh, red4, tid);
    if (tid == 0) chars_out[TLEN - 1] = (float)idx;
}

// ================= phase B: logits[t][j] = W_head[j]·h_t + b_head[j] =================
#define GJ 64
#define GT 128
#define GK 16
__global__ __launch_bounds__(256) void k_gemm(const float* __restrict__ W_head,
                                              const float* __restrict__ b_head,
                                              const float* __restrict__ hh,
                                              float* __restrict__ logits)
{
    __shared__ float Ws[GK][GJ + 4];
    __shared__ float Hs[GK][GT + 1];

    const int tid = threadIdx.x;
    const int j0 = blockIdx.x * GJ;
    const int t0 = blockIdx.y * GT;
    const int tj = tid & 15;        // 16 j-groups (x4 j each)
    const int tt = tid >> 4;        // 16 t-groups (x8 t each)

    // loader indices
    const int wlj = tid >> 2;             // 0..63
    const int wlk = (tid & 3) * 4;        // 0,4,8,12
    const int hlt = tid >> 1;             // 0..127
    const int hlk = (tid & 1) * 8;        // 0 or 8
    const float* Wrow = W_head + (size_t)(j0 + wlj) * HID;
    const bool wvalid = (j0 + wlj) < NC;

    float acc[8][4];
    #pragma unroll
    for (int b = 0; b < 8; ++b)
        #pragma unroll
        for (int a = 0; a < 4; ++a) acc[b][a] = 0.f;

    for (int k0 = 0; k0 < HID; k0 += GK) {
        __syncthreads();
        float4 wv = wvalid ? *(const float4*)(Wrow + k0 + wlk) : make_float4(0, 0, 0, 0);
        Ws[wlk + 0][wlj] = wv.x; Ws[wlk + 1][wlj] = wv.y;
        Ws[wlk + 2][wlj] = wv.z; Ws[wlk + 3][wlj] = wv.w;
        const float* hp = hh + (size_t)(t0 + hlt + 1) * HID + k0 + hlk;
        float4 a0 = *(const float4*)hp;
        float4 a1 = *(const float4*)(hp + 4);
        Hs[hlk + 0][hlt] = a0.x; Hs[hlk + 1][hlt] = a0.y;
        Hs[hlk + 2][hlt] = a0.z; Hs[hlk + 3][hlt] = a0.w;
        Hs[hlk + 4][hlt] = a1.x; Hs[hlk + 5][hlt] = a1.y;
        Hs[hlk + 6][hlt] = a1.z; Hs[hlk + 7][hlt] = a1.w;
        __syncthreads();
        #pragma unroll
        for (int kk = 0; kk < GK; ++kk) {
            float4 w4 = *(const float4*)&Ws[kk][tj * 4];
            float hvv[8];
            #pragma unroll
            for (int b = 0; b < 8; ++b) hvv[b] = Hs[kk][tt + 16 * b];
            #pragma unroll
            for (int b = 0; b < 8; ++b) {
                acc[b][0] = fmaf(w4.x, hvv[b], acc[b][0]);
                acc[b][1] = fmaf(w4.y, hvv[b], acc[b][1]);
                acc[b][2] = fmaf(w4.z, hvv[b], acc[b][2]);
                acc[b][3] = fmaf(w4.w, hvv[b], acc[b][3]);
            }
        }
    }

    const int j = j0 + tj * 4;
    float b0 = (j + 0 < NC) ? b_head[j + 0] : 0.f;
    float b1 = (j + 1 < NC) ? b_head[j + 1] : 0.f;
    float b2 = (j + 2 < NC) ? b_head[j + 2] : 0.f;
    float b3 = (j + 3 < NC) ? b_head[j + 3] : 0.f;
    #pragma unroll
    for (int b = 0; b < 8; ++b) {
        const int t = t0 + tt + 16 * b;
        float* dst = logits + (size_t)t * NC + j;
        if (j + 3 < NC) {
            f32x4 o = { acc[b][0] + b0, acc[b][1] + b1,
                        acc[b][2] + b2, acc[b][3] + b3 };
            __builtin_nontemporal_store(o, (f32x4*)dst);
        } else {
            if (j + 0 < NC) dst[0] = acc[b][0] + b0;
            if (j + 1 < NC) dst[1] = acc[b][1] + b1;
            if (j + 2 < NC) dst[2] = acc[b][2] + b2;
        }
    }
}

// ======================================================================
// ===================== fallback (round-1, proven) =====================
// ======================================================================
__global__ __launch_bounds__(256) void k_init_fb(const float* __restrict__ inputs,
                                                 const int* __restrict__ startp,
                                                 float* __restrict__ h0,
                                                 float* __restrict__ c,
                                                 ull* __restrict__ blockmax)
{
    int tid = blockIdx.x * 256 + threadIdx.x;
    if (tid < NBH) blockmax[tid] = (tid == 0) ? packkv(3.0e38f, (unsigned)startp[0]) : 0ull;
    if (tid < HID) { h0[tid] = inputs[tid]; c[tid] = 0.f; }
}

__global__ __launch_bounds__(256) void k_lstm_fb(const float* __restrict__ W_ih,
                                                 const float* __restrict__ W_hh,
                                                 const float* __restrict__ b_ih,
                                                 const float* __restrict__ b_hh,
                                                 const float* __restrict__ embed,
                                                 const ull* __restrict__ blockmax,
                                                 const float* __restrict__ h_in,
                                                 float* __restrict__ h_out,
                                                 float* __restrict__ c,
                                                 float* __restrict__ chars_out,
                                                 int t)
{
    __shared__ float4 xs4[CHARD / 4];
    __shared__ float4 hs4[HID / 4];
    __shared__ ull    red[256];
    const int tid = threadIdx.x;
    ull pm = 0ull;
    for (int i = tid; i < NBH; i += 256) pm = umaxu(pm, blockmax[i]);
    red[tid] = pm;
    __syncthreads();
    for (int s = 128; s > 0; s >>= 1) {
        if (tid < s) red[tid] = umaxu(red[tid], red[tid + s]);
        __syncthreads();
    }
    const unsigned idx = 0xFFFFFFFFu - (unsigned)(red[0] & 0xFFFFFFFFull);
    if (t > 0 && blockIdx.x == 0 && tid == 0) chars_out[t - 1] = (float)idx;
    const float4* ex = (const float4*)(embed + (size_t)idx * CHARD);
    if (tid < 128) xs4[tid] = ex[tid];
    hs4[tid] = ((const float4*)h_in)[tid];
    __syncthreads();
    const int wave = tid >> 6, lane = tid & 63;
    const int r = blockIdx.x * 4 + wave;
    float acc[4];
    #pragma unroll
    for (int q = 0; q < 4; ++q) {
        const float4* wi = (const float4*)(W_ih + (size_t)(q * HID + r) * CHARD);
        const float4* wh = (const float4*)(W_hh + (size_t)(q * HID + r) * HID);
        float a = 0.f;
        #pragma unroll
        for (int m = 0; m < 2; ++m) {
            float4 w = wi[m * 64 + lane], v = xs4[m * 64 + lane];
            a = fmaf(w.x, v.x, a); a = fmaf(w.y, v.y, a);
            a = fmaf(w.z, v.z, a); a = fmaf(w.w, v.w, a);
        }
        #pragma unroll
        for (int m = 0; m < 4; ++m) {
            float4 w = wh[m * 64 + lane], v = hs4[m * 64 + lane];
            a = fmaf(w.x, v.x, a); a = fmaf(w.y, v.y, a);
            a = fmaf(w.z, v.z, a); a = fmaf(w.w, v.w, a);
        }
        acc[q] = a;
    }
    #pragma unroll
    for (int q = 0; q < 4; ++q)
        #pragma unroll
        for (int off = 32; off > 0; off >>= 1) acc[q] += __shfl_xor(acc[q], off);
    if (lane == 0) {
        float zi = acc[0] + b_ih[r]           + b_hh[r];
        float zf = acc[1] + b_ih[HID + r]     + b_hh[HID + r];
        float zg = acc[2] + b_ih[2 * HID + r] + b_hh[2 * HID + r];
        float zo = acc[3] + b_ih[3 * HID + r] + b_hh[3 * HID + r];
        float ig = 1.f / (1.f + expf(-zi));
        float fg = 1.f / (1.f + expf(-zf));
        float gg = tanhf(zg);
        float og = 1.f / (1.f + expf(-zo));
        float cn = fg * c[r] + ig * gg;
        c[r] = cn;
        h_out[r] = og * tanhf(cn);
    }
}

__global__ __launch_bounds__(256) void k_head_fb(const float* __restrict__ W_head,
                                                 const float* __restrict__ b_head,
                                                 const float* __restrict__ h_in,
                                                 float* __restrict__ logits,
                                                 ull* __restrict__ blockmax)
{
    __shared__ float4 hs4[HID / 4];
    __shared__ ull    wmax[4];
    const int tid = threadIdx.x;
    hs4[tid] = ((const float4*)h_in)[tid];
    __syncthreads();
    const int wave = tid >> 6, lane = tid & 63;
    const int base = blockIdx.x * 32 + wave * 8;
    ull pm = 0ull;
    #pragma unroll
    for (int rep = 0; rep < 8; ++rep) {
        const int j = base + rep;
        if (j < NC) {
            const float4* w = (const float4*)(W_head + (size_t)j * HID);
            float a = 0.f;
            #pragma unroll
            for (int m = 0; m < 4; ++m) {
                float4 ww = w[m * 64 + lane], v = hs4[m * 64 + lane];
                a = fmaf(ww.x, v.x, a); a = fmaf(ww.y, v.y, a);
                a = fmaf(ww.z, v.z, a); a = fmaf(ww.w, v.w, a);
            }
            #pragma unroll
            for (int off = 32; off > 0; off >>= 1) a += __shfl_xor(a, off);
            const float v = a + b_head[j];
            if (lane == 0) __builtin_nontemporal_store(v, &logits[j]);
            pm = umaxu(pm, packkv(v, (unsigned)j));
        }
    }
    if (lane == 0) wmax[wave] = pm;
    __syncthreads();
    if (tid == 0)
        blockmax[blockIdx.x] = umaxu(umaxu(wmax[0], wmax[1]), umaxu(wmax[2], wmax[3]));
}

__global__ __launch_bounds__(256) void k_final_fb(const ull* __restrict__ blockmax,
                                                  float* __restrict__ chars_out)
{
    __shared__ ull red[256];
    const int tid = threadIdx.x;
    ull pm = 0ull;
    for (int i = tid; i < NBH; i += 256) pm = umaxu(pm, blockmax[i]);
    red[tid] = pm;
    __syncthreads();
    for (int s = 128; s > 0; s >>= 1) {
        if (tid < s) red[tid] = umaxu(red[tid], red[tid + s]);
        __syncthreads();
    }
    if (tid == 0)
        chars_out[TLEN - 1] = (float)(0xFFFFFFFFu - (unsigned)(red[0] & 0xFFFFFFFFull));
}

// ======================================================================
extern "C" void kernel_launch(void* const* d_in, const int* in_sizes, int n_in,
                              void* d_out, int out_size, void* d_ws, size_t ws_size,
                              hipStream_t stream)
{
    const float* inputs = (const float*)d_in[0];
    const float* embed  = (const float*)d_in[1];
    const float* W_ih   = (const float*)d_in[2];
    const float* W_hh   = (const float*)d_in[3];
    const float* b_ih   = (const float*)d_in[4];
    const float* b_hh   = (const float*)d_in[5];
    const float* W_head = (const float*)d_in[6];
    const float* b_head = (const float*)d_in[7];
    const int*   startp = (const int*)d_in[9];

    float* out        = (float*)d_out;
    float* chars_out  = out;          // [2048]
    float* logits_out = out + TLEN;   // [2048 * 50257]

    char* ws = (char*)d_ws;
    const size_t off_hh = 0;
    const size_t off_c  = off_hh + (size_t)(TLEN + 1) * HID * 4;           // 8,392,704
    const size_t off_ab = off_c + (size_t)HID * 4;                         // 8,396,800
    const size_t off_bm = (off_ab + (size_t)NC * 4 + 7) & ~(size_t)7;
    const size_t off_w8 = (off_bm + (size_t)NBS * 8 + 15) & ~(size_t)15;
    const size_t need   = off_w8 + (size_t)NC * HID;

    if (ws_size >= need) {
        float* hh   = (float*)(ws + off_hh);   // hh[s] = h after s steps; hh[0]=h0
        float* c    = (float*)(ws + off_c);
        float* abuf = (float*)(ws + off_ab);
        ull*   bm   = (ull*)(ws + off_bm);
        u8*    W8   = (u8*)(ws + off_w8);

        hipLaunchKernelGGL(k_init, dim3(4), dim3(256), 0, stream, inputs, hh, c);
        hipLaunchKernelGGL(k_quant, dim3((NC * HID / 16 + 255) / 256), dim3(256), 0, stream,
                           W_head, W8);

        for (int t = 0; t < TLEN; ++t) {
            hipLaunchKernelGGL(k_lstm, dim3(256), dim3(256), 0, stream,
                               W_ih, W_hh, b_ih, b_hh, embed, W_head, b_head,
                               bm, abuf, hh + (size_t)t * HID, hh + (size_t)(t + 1) * HID,
                               c, chars_out, startp, t);
            hipLaunchKernelGGL(k_screen, dim3(NBS), dim3(256), 0, stream,
                               W8, b_head, hh + (size_t)(t + 1) * HID, abuf, bm);
        }
        hipLaunchKernelGGL(k_finalc, dim3(1), dim3(256), 0, stream,
                           hh + (size_t)TLEN * HID, bm, abuf, W_head, b_head, chars_out);
        hipLaunchKernelGGL(k_gemm, dim3((NC + GJ - 1) / GJ, TLEN / GT), dim3(256), 0, stream,
                           W_head, b_head, hh, logits_out);
    } else {
        // fallback: round-1 path (needs ~25 KB ws)
        float* h0 = (float*)(ws);
        float* h1 = (float*)(ws + 4096);
        float* c  = (float*)(ws + 8192);
        ull* blockmax = (ull*)(ws + 12288);
        hipLaunchKernelGGL(k_init_fb, dim3(7), dim3(256), 0, stream,
                           inputs, startp, h0, c, blockmax);
        for (int t = 0; t < TLEN; ++t) {
            const float* hin = (t & 1) ? h1 : h0;
            float*       hout = (t & 1) ? h0 : h1;
            hipLaunchKernelGGL(k_lstm_fb, dim3(256), dim3(256), 0, stream,
                               W_ih, W_hh, b_ih, b_hh, embed, blockmax,
                               hin, hout, c, chars_out, t);
            hipLaunchKernelGGL(k_head_fb, dim3(NBH), dim3(256), 0, stream,
                               W_head, b_head, hout,
                               logits_out + (size_t)t * NC, blockmax);
        }
        hipLaunchKernelGGL(k_final_fb, dim3(1), dim3(256), 0, stream, blockmax, chars_out);
    }
}

// Round 4
// 54270.642 us; speedup vs baseline: 2.9950x; 2.9950x over previous
//
#include <hip/hip_runtime.h>
#include <stdint.h>
#include <math.h>

#define HID   1024
#define CHARD 512
#define NC    50257
#define TLEN  2048
#define NBS   1571          // screen blocks: 32 rows each -> 50272 >= 50257
#define NBH   1571          // fallback head blocks
#define SQ    4064.0f       // 127 / 0.03125
#define INVSQ (1.0f/4064.0f)
#define QERR  (0.5f/4064.0f)
#define CANDR 256           // candidate-row LDS list capacity

typedef unsigned long long ull;
typedef unsigned char u8;
typedef float f32x4 __attribute__((ext_vector_type(4)));

__device__ __forceinline__ unsigned ford(float f) {
    unsigned b = __float_as_uint(f);
    return (b & 0x80000000u) ? ~b : (b | 0x80000000u);
}
__device__ __forceinline__ float unford(unsigned u) {
    return __uint_as_float((u & 0x80000000u) ? (u & 0x7FFFFFFFu) : ~u);
}
__device__ __forceinline__ ull packkv(float v, unsigned j) {
    return ((ull)ford(v) << 32) | (ull)(0xFFFFFFFFu - j);
}
__device__ __forceinline__ ull umaxu(ull a, ull b) { return a > b ? a : b; }
__device__ __forceinline__ ull shflx_ull(ull v, int m) {
    unsigned lo = (unsigned)v, hi = (unsigned)(v >> 32);
    lo = __shfl_xor(lo, m);
    hi = __shfl_xor(hi, m);
    return ((ull)hi << 32) | lo;
}

// ================= init: hh[0] = inputs, c = 0 =================
__global__ __launch_bounds__(256) void k_init(const float* __restrict__ inputs,
                                              float* __restrict__ hh,
                                              float* __restrict__ c)
{
    int tid = blockIdx.x * 256 + threadIdx.x;
    if (tid < HID) { hh[tid] = inputs[tid]; c[tid] = 0.f; }
}

// ================= quantize W_head -> int8 (scale SQ) =================
__global__ __launch_bounds__(256) void k_quant(const float* __restrict__ W,
                                               u8* __restrict__ W8)
{
    size_t base = ((size_t)blockIdx.x * 256 + threadIdx.x) * 16;
    if (base >= (size_t)NC * HID) return;
    const float4* src = (const float4*)(W + base);
    uint out[4];
    #pragma unroll
    for (int g = 0; g < 4; ++g) {
        float4 w = src[g];
        int a0 = __float2int_rn(w.x * SQ) & 255;
        int a1 = __float2int_rn(w.y * SQ) & 255;
        int a2 = __float2int_rn(w.z * SQ) & 255;
        int a3 = __float2int_rn(w.w * SQ) & 255;
        out[g] = (uint)(a0 | (a1 << 8) | (a2 << 16) | (a3 << 24));
    }
    *(uint4*)(W8 + base) = make_uint4(out[0], out[1], out[2], out[3]);
}

// ================= exact dot of W_head row j with staged h =================
__device__ __forceinline__ float exact_logit(const float4* hs4,
                                             const float* __restrict__ W_head,
                                             const float* __restrict__ b_head,
                                             int j, int lane)
{
    const float4* wr = (const float4*)(W_head + (size_t)j * HID);
    float a = 0.f;
    #pragma unroll
    for (int m = 0; m < 4; ++m) {
        float4 w = wr[m * 64 + lane], v = hs4[m * 64 + lane];
        a = fmaf(w.x, v.x, a); a = fmaf(w.y, v.y, a);
        a = fmaf(w.z, v.z, a); a = fmaf(w.w, v.w, a);
    }
    #pragma unroll
    for (int off = 32; off > 0; off >>= 1) a += __shfl_xor(a, off);
    return a + b_head[j];
}

// ================= resolve exact argmax of previous step =================
// Screen guarantees |abuf[j] - logit[j]| <= E. Candidates = rows with
// abuf >= mtil - 2E (provably contains true argmax). Collect candidates
// PARALLEL (no data-dependent serialized loop), then exact fp32 recompute.
__device__ __forceinline__ unsigned resolve_char(const float4* hs4,
                                                 const ull* __restrict__ blockmax,
                                                 const float* __restrict__ abuf,
                                                 const float* __restrict__ W_head,
                                                 const float* __restrict__ b_head,
                                                 float Sh, ull* red4, int tid)
{
    __shared__ int s_cnt;
    __shared__ int s_rows[CANDR];

    const int wave = tid >> 6;
    const int lane = tid & 63;

    // ---- pass 1: global screen max (independent strided loads, pipelined)
    ull pm = 0ull;
    for (int i = tid; i < NBS; i += 256) pm = umaxu(pm, blockmax[i]);
    #pragma unroll
    for (int off = 32; off > 0; off >>= 1) pm = umaxu(pm, shflx_ull(pm, off));
    if (lane == 0) red4[wave] = pm;
    if (tid == 0) s_cnt = 0;
    __syncthreads();
    pm = umaxu(umaxu(red4[0], red4[1]), umaxu(red4[2], red4[3]));
    const float mtil = unford((unsigned)(pm >> 32));
    const float E = QERR * Sh * 1.02f + 1e-4f;
    const float thresh = mtil - 2.0f * E;
    const ull pkth = ((ull)ford(thresh)) << 32;
    __syncthreads();

    // ---- pass 2: parallel candidate-row collection into LDS
    for (int i = tid; i < NBS; i += 256) {
        if (blockmax[i] >= pkth) {
            const int jbase = i * 32;
            #pragma unroll
            for (int r = 0; r < 32; ++r) {
                const int j = jbase + r;
                if (j < NC && abuf[j] >= thresh) {
                    int p = atomicAdd(&s_cnt, 1);
                    if (p < CANDR) s_rows[p] = j;
                }
            }
        }
    }
    __syncthreads();
    const int ncr = s_cnt;

    // ---- pass 3: exact fp32 recompute of candidates
    ull best = 0ull;
    if (ncr <= CANDR) {
        for (int q = wave; q < ncr; q += 4) {
            const int j = s_rows[q];
            const float v = exact_logit(hs4, W_head, b_head, j, lane);
            best = umaxu(best, packkv(v, (unsigned)j));
        }
    } else {
        // overflow fallback (pathological; never expected): exhaustive scan
        for (int i = wave; i < NBS; i += 4) {
            if (blockmax[i] >= pkth) {
                const int jbase = i * 32;
                for (int rr = 0; rr < 32; ++rr) {
                    const int j = jbase + rr;
                    if (j >= NC) break;
                    if (abuf[j] >= thresh) {
                        const float v = exact_logit(hs4, W_head, b_head, j, lane);
                        best = umaxu(best, packkv(v, (unsigned)j));
                    }
                }
            }
        }
    }
    __syncthreads();          // red4 reuse safety
    if (lane == 0) red4[wave] = best;
    __syncthreads();
    best = umaxu(umaxu(red4[0], red4[1]), umaxu(red4[2], red4[3]));
    unsigned idx = 0xFFFFFFFFu - (unsigned)(best & 0xFFFFFFFFull);
    return idx < NC ? idx : (NC - 1);
}

// ================= LSTM step (+ exact argmax of prev step) =================
__global__ __launch_bounds__(256) void k_lstm(const float* __restrict__ W_ih,
                                              const float* __restrict__ W_hh,
                                              const float* __restrict__ b_ih,
                                              const float* __restrict__ b_hh,
                                              const float* __restrict__ embed,
                                              const float* __restrict__ W_head,
                                              const float* __restrict__ b_head,
                                              const ull* __restrict__ blockmax,
                                              const float* __restrict__ abuf,
                                              const float* __restrict__ h_in,
                                              float* __restrict__ h_out,
                                              float* __restrict__ c,
                                              float* __restrict__ chars_out,
                                              const int* __restrict__ startp,
                                              int t)
{
    __shared__ float4 xs4[CHARD / 4];   // 128
    __shared__ float4 hs4[HID / 4];     // 256
    __shared__ ull    red4[4];
    __shared__ float  sred[4];

    const int tid  = threadIdx.x;
    const int wave = tid >> 6;
    const int lane = tid & 63;

    // stage h + sum |h|
    float4 hv = ((const float4*)h_in)[tid];
    hs4[tid] = hv;
    float sa = fabsf(hv.x) + fabsf(hv.y) + fabsf(hv.z) + fabsf(hv.w);
    #pragma unroll
    for (int off = 32; off > 0; off >>= 1) sa += __shfl_xor(sa, off);
    if (lane == 0) sred[wave] = sa;
    __syncthreads();
    const float Sh = sred[0] + sred[1] + sred[2] + sred[3];

    unsigned idx;
    if (t == 0) {
        idx = (unsigned)startp[0];
    } else {
        idx = resolve_char(hs4, blockmax, abuf, W_head, b_head, Sh, red4, tid);
        if (blockIdx.x == 0 && tid == 0) chars_out[t - 1] = (float)idx;
    }

    // stage x = embed[idx]
    const float4* ex = (const float4*)(embed + (size_t)idx * CHARD);
    if (tid < 128) xs4[tid] = ex[tid];
    __syncthreads();

    const int r = blockIdx.x * 4 + wave;   // output element 0..1023

    float acc[4];
    #pragma unroll
    for (int q = 0; q < 4; ++q) {
        const float4* wi = (const float4*)(W_ih + (size_t)(q * HID + r) * CHARD);
        const float4* wh = (const float4*)(W_hh + (size_t)(q * HID + r) * HID);
        float a = 0.f;
        #pragma unroll
        for (int m = 0; m < 2; ++m) {
            float4 w = wi[m * 64 + lane], v = xs4[m * 64 + lane];
            a = fmaf(w.x, v.x, a); a = fmaf(w.y, v.y, a);
            a = fmaf(w.z, v.z, a); a = fmaf(w.w, v.w, a);
        }
        #pragma unroll
        for (int m = 0; m < 4; ++m) {
            float4 w = wh[m * 64 + lane], v = hs4[m * 64 + lane];
            a = fmaf(w.x, v.x, a); a = fmaf(w.y, v.y, a);
            a = fmaf(w.z, v.z, a); a = fmaf(w.w, v.w, a);
        }
        acc[q] = a;
    }
    #pragma unroll
    for (int q = 0; q < 4; ++q) {
        #pragma unroll
        for (int off = 32; off > 0; off >>= 1) acc[q] += __shfl_xor(acc[q], off);
    }

    if (lane == 0) {
        float zi = acc[0] + b_ih[r]           + b_hh[r];
        float zf = acc[1] + b_ih[HID + r]     + b_hh[HID + r];
        float zg = acc[2] + b_ih[2 * HID + r] + b_hh[2 * HID + r];
        float zo = acc[3] + b_ih[3 * HID + r] + b_hh[3 * HID + r];
        float ig = 1.f / (1.f + expf(-zi));
        float fg = 1.f / (1.f + expf(-zf));
        float gg = tanhf(zg);
        float og = 1.f / (1.f + expf(-zo));
        float cn = fg * c[r] + ig * gg;
        c[r] = cn;
        h_out[r] = og * tanhf(cn);
    }
}

// ================= int8 screening head =================
__global__ __launch_bounds__(256) void k_screen(const u8* __restrict__ W8,
                                                const float* __restrict__ b_head,
                                                const float* __restrict__ h_in,
                                                float* __restrict__ abuf,
                                                ull* __restrict__ blockmax)
{
    __shared__ float4 hs4[HID / 4];
    __shared__ ull    wred[4];

    const int tid  = threadIdx.x;
    const int wave = tid >> 6;
    const int lane = tid & 63;

    hs4[tid] = ((const float4*)h_in)[tid];
    __syncthreads();

    const float4 h0 = hs4[lane * 4 + 0];
    const float4 h1 = hs4[lane * 4 + 1];
    const float4 h2 = hs4[lane * 4 + 2];
    const float4 h3 = hs4[lane * 4 + 3];

    const int base = blockIdx.x * 32 + wave * 8;
    ull pm = 0ull;
    #pragma unroll
    for (int rep = 0; rep < 8; ++rep) {
        const int j = base + rep;
        if (j < NC) {
            uint4 q = ((const uint4*)(W8 + (size_t)j * HID))[lane];
            float a = 0.f;
            a = fmaf((float)((int)(q.x << 24) >> 24), h0.x, a);
            a = fmaf((float)((int)(q.x << 16) >> 24), h0.y, a);
            a = fmaf((float)((int)(q.x <<  8) >> 24), h0.z, a);
            a = fmaf((float)((int)(q.x      ) >> 24), h0.w, a);
            a = fmaf((float)((int)(q.y << 24) >> 24), h1.x, a);
            a = fmaf((float)((int)(q.y << 16) >> 24), h1.y, a);
            a = fmaf((float)((int)(q.y <<  8) >> 24), h1.z, a);
            a = fmaf((float)((int)(q.y      ) >> 24), h1.w, a);
            a = fmaf((float)((int)(q.z << 24) >> 24), h2.x, a);
            a = fmaf((float)((int)(q.z << 16) >> 24), h2.y, a);
            a = fmaf((float)((int)(q.z <<  8) >> 24), h2.z, a);
            a = fmaf((float)((int)(q.z      ) >> 24), h2.w, a);
            a = fmaf((float)((int)(q.w << 24) >> 24), h3.x, a);
            a = fmaf((float)((int)(q.w << 16) >> 24), h3.y, a);
            a = fmaf((float)((int)(q.w <<  8) >> 24), h3.z, a);
            a = fmaf((float)((int)(q.w      ) >> 24), h3.w, a);
            #pragma unroll
            for (int off = 32; off > 0; off >>= 1) a += __shfl_xor(a, off);
            const float v = a * INVSQ + b_head[j];
            if (lane == 0) abuf[j] = v;
            pm = umaxu(pm, packkv(v, (unsigned)j));
        }
    }
    if (lane == 0) wred[wave] = pm;
    __syncthreads();
    if (tid == 0)
        blockmax[blockIdx.x] = umaxu(umaxu(wred[0], wred[1]), umaxu(wred[2], wred[3]));
}

// ================= final char (t = TLEN-1) =================
__global__ __launch_bounds__(256) void k_finalc(const float* __restrict__ h_in,
                                                const ull* __restrict__ blockmax,
                                                const float* __restrict__ abuf,
                                                const float* __restrict__ W_head,
                                                const float* __restrict__ b_head,
                                                float* __restrict__ chars_out)
{
    __shared__ float4 hs4[HID / 4];
    __shared__ ull    red4[4];
    __shared__ float  sred[4];
    const int tid  = threadIdx.x;
    const int wave = tid >> 6;
    const int lane = tid & 63;

    float4 hv = ((const float4*)h_in)[tid];
    hs4[tid] = hv;
    float sa = fabsf(hv.x) + fabsf(hv.y) + fabsf(hv.z) + fabsf(hv.w);
    #pragma unroll
    for (int off = 32; off > 0; off >>= 1) sa += __shfl_xor(sa, off);
    if (lane == 0) sred[wave] = sa;
    __syncthreads();
    const float Sh = sred[0] + sred[1] + sred[2] + sred[3];
    unsigned idx = resolve_char(hs4, blockmax, abuf, W_head, b_head, Sh, red4, tid);
    if (tid == 0) chars_out[TLEN - 1] = (float)idx;
}

// ================= phase B: logits[t][j] = W_head[j]·h_t + b_head[j] =================
#define GJ 64
#define GT 128
#define GK 16
__global__ __launch_bounds__(256) void k_gemm(const float* __restrict__ W_head,
                                              const float* __restrict__ b_head,
                                              const float* __restrict__ hh,
                                              float* __restrict__ logits)
{
    __shared__ float Ws[GK][GJ + 4];
    __shared__ float Hs[GK][GT + 1];

    const int tid = threadIdx.x;
    const int j0 = blockIdx.x * GJ;
    const int t0 = blockIdx.y * GT;
    const int tj = tid & 15;        // 16 j-groups (x4 j each)
    const int tt = tid >> 4;        // 16 t-groups (x8 t each)

    const int wlj = tid >> 2;             // 0..63
    const int wlk = (tid & 3) * 4;        // 0,4,8,12
    const int hlt = tid >> 1;             // 0..127
    const int hlk = (tid & 1) * 8;        // 0 or 8
    const float* Wrow = W_head + (size_t)(j0 + wlj) * HID;
    const bool wvalid = (j0 + wlj) < NC;

    float acc[8][4];
    #pragma unroll
    for (int b = 0; b < 8; ++b)
        #pragma unroll
        for (int a = 0; a < 4; ++a) acc[b][a] = 0.f;

    for (int k0 = 0; k0 < HID; k0 += GK) {
        __syncthreads();
        float4 wv = wvalid ? *(const float4*)(Wrow + k0 + wlk) : make_float4(0, 0, 0, 0);
        Ws[wlk + 0][wlj] = wv.x; Ws[wlk + 1][wlj] = wv.y;
        Ws[wlk + 2][wlj] = wv.z; Ws[wlk + 3][wlj] = wv.w;
        const float* hp = hh + (size_t)(t0 + hlt + 1) * HID + k0 + hlk;
        float4 a0 = *(const float4*)hp;
        float4 a1 = *(const float4*)(hp + 4);
        Hs[hlk + 0][hlt] = a0.x; Hs[hlk + 1][hlt] = a0.y;
        Hs[hlk + 2][hlt] = a0.z; Hs[hlk + 3][hlt] = a0.w;
        Hs[hlk + 4][hlt] = a1.x; Hs[hlk + 5][hlt] = a1.y;
        Hs[hlk + 6][hlt] = a1.z; Hs[hlk + 7][hlt] = a1.w;
        __syncthreads();
        #pragma unroll
        for (int kk = 0; kk < GK; ++kk) {
            float4 w4 = *(const float4*)&Ws[kk][tj * 4];
            float hvv[8];
            #pragma unroll
            for (int b = 0; b < 8; ++b) hvv[b] = Hs[kk][tt + 16 * b];
            #pragma unroll
            for (int b = 0; b < 8; ++b) {
                acc[b][0] = fmaf(w4.x, hvv[b], acc[b][0]);
                acc[b][1] = fmaf(w4.y, hvv[b], acc[b][1]);
                acc[b][2] = fmaf(w4.z, hvv[b], acc[b][2]);
                acc[b][3] = fmaf(w4.w, hvv[b], acc[b][3]);
            }
        }
    }

    const int j = j0 + tj * 4;
    float b0 = (j + 0 < NC) ? b_head[j + 0] : 0.f;
    float b1 = (j + 1 < NC) ? b_head[j + 1] : 0.f;
    float b2 = (j + 2 < NC) ? b_head[j + 2] : 0.f;
    float b3 = (j + 3 < NC) ? b_head[j + 3] : 0.f;
    #pragma unroll
    for (int b = 0; b < 8; ++b) {
        const int t = t0 + tt + 16 * b;
        float* dst = logits + (size_t)t * NC + j;
        if (j + 3 < NC) {
            f32x4 o = { acc[b][0] + b0, acc[b][1] + b1,
                        acc[b][2] + b2, acc[b][3] + b3 };
            __builtin_nontemporal_store(o, (f32x4*)dst);
        } else {
            if (j + 0 < NC) dst[0] = acc[b][0] + b0;
            if (j + 1 < NC) dst[1] = acc[b][1] + b1;
            if (j + 2 < NC) dst[2] = acc[b][2] + b2;
        }
    }
}

// ======================================================================
// ===================== fallback (round-1, proven) =====================
// ======================================================================
__global__ __launch_bounds__(256) void k_init_fb(const float* __restrict__ inputs,
                                                 const int* __restrict__ startp,
                                                 float* __restrict__ h0,
                                                 float* __restrict__ c,
                                                 ull* __restrict__ blockmax)
{
    int tid = blockIdx.x * 256 + threadIdx.x;
    if (tid < NBH) blockmax[tid] = (tid == 0) ? packkv(3.0e38f, (unsigned)startp[0]) : 0ull;
    if (tid < HID) { h0[tid] = inputs[tid]; c[tid] = 0.f; }
}

__global__ __launch_bounds__(256) void k_lstm_fb(const float* __restrict__ W_ih,
                                                 const float* __restrict__ W_hh,
                                                 const float* __restrict__ b_ih,
                                                 const float* __restrict__ b_hh,
                                                 const float* __restrict__ embed,
                                                 const ull* __restrict__ blockmax,
                                                 const float* __restrict__ h_in,
                                                 float* __restrict__ h_out,
                                                 float* __restrict__ c,
                                                 float* __restrict__ chars_out,
                                                 int t)
{
    __shared__ float4 xs4[CHARD / 4];
    __shared__ float4 hs4[HID / 4];
    __shared__ ull    red[256];
    const int tid = threadIdx.x;
    ull pm = 0ull;
    for (int i = tid; i < NBH; i += 256) pm = umaxu(pm, blockmax[i]);
    red[tid] = pm;
    __syncthreads();
    for (int s = 128; s > 0; s >>= 1) {
        if (tid < s) red[tid] = umaxu(red[tid], red[tid + s]);
        __syncthreads();
    }
    const unsigned idx = 0xFFFFFFFFu - (unsigned)(red[0] & 0xFFFFFFFFull);
    if (t > 0 && blockIdx.x == 0 && tid == 0) chars_out[t - 1] = (float)idx;
    const float4* ex = (const float4*)(embed + (size_t)idx * CHARD);
    if (tid < 128) xs4[tid] = ex[tid];
    hs4[tid] = ((const float4*)h_in)[tid];
    __syncthreads();
    const int wave = tid >> 6, lane = tid & 63;
    const int r = blockIdx.x * 4 + wave;
    float acc[4];
    #pragma unroll
    for (int q = 0; q < 4; ++q) {
        const float4* wi = (const float4*)(W_ih + (size_t)(q * HID + r) * CHARD);
        const float4* wh = (const float4*)(W_hh + (size_t)(q * HID + r) * HID);
        float a = 0.f;
        #pragma unroll
        for (int m = 0; m < 2; ++m) {
            float4 w = wi[m * 64 + lane], v = xs4[m * 64 + lane];
            a = fmaf(w.x, v.x, a); a = fmaf(w.y, v.y, a);
            a = fmaf(w.z, v.z, a); a = fmaf(w.w, v.w, a);
        }
        #pragma unroll
        for (int m = 0; m < 4; ++m) {
            float4 w = wh[m * 64 + lane], v = hs4[m * 64 + lane];
            a = fmaf(w.x, v.x, a); a = fmaf(w.y, v.y, a);
            a = fmaf(w.z, v.z, a); a = fmaf(w.w, v.w, a);
        }
        acc[q] = a;
    }
    #pragma unroll
    for (int q = 0; q < 4; ++q)
        #pragma unroll
        for (int off = 32; off > 0; off >>= 1) acc[q] += __shfl_xor(acc[q], off);
    if (lane == 0) {
        float zi = acc[0] + b_ih[r]           + b_hh[r];
        float zf = acc[1] + b_ih[HID + r]     + b_hh[HID + r];
        float zg = acc[2] + b_ih[2 * HID + r] + b_hh[2 * HID + r];
        float zo = acc[3] + b_ih[3 * HID + r] + b_hh[3 * HID + r];
        float ig = 1.f / (1.f + expf(-zi));
        float fg = 1.f / (1.f + expf(-zf));
        float gg = tanhf(zg);
        float og = 1.f / (1.f + expf(-zo));
        float cn = fg * c[r] + ig * gg;
        c[r] = cn;
        h_out[r] = og * tanhf(cn);
    }
}

__global__ __launch_bounds__(256) void k_head_fb(const float* __restrict__ W_head,
                                                 const float* __restrict__ b_head,
                                                 const float* __restrict__ h_in,
                                                 float* __restrict__ logits,
                                                 ull* __restrict__ blockmax)
{
    __shared__ float4 hs4[HID / 4];
    __shared__ ull    wmax[4];
    const int tid = threadIdx.x;
    hs4[tid] = ((const float4*)h_in)[tid];
    __syncthreads();
    const int wave = tid >> 6, lane = tid & 63;
    const int base = blockIdx.x * 32 + wave * 8;
    ull pm = 0ull;
    #pragma unroll
    for (int rep = 0; rep < 8; ++rep) {
        const int j = base + rep;
        if (j < NC) {
            const float4* w = (const float4*)(W_head + (size_t)j * HID);
            float a = 0.f;
            #pragma unroll
            for (int m = 0; m < 4; ++m) {
                float4 ww = w[m * 64 + lane], v = hs4[m * 64 + lane];
                a = fmaf(ww.x, v.x, a); a = fmaf(ww.y, v.y, a);
                a = fmaf(ww.z, v.z, a); a = fmaf(ww.w, v.w, a);
            }
            #pragma unroll
            for (int off = 32; off > 0; off >>= 1) a += __shfl_xor(a, off);
            const float v = a + b_head[j];
            if (lane == 0) __builtin_nontemporal_store(v, &logits[j]);
            pm = umaxu(pm, packkv(v, (unsigned)j));
        }
    }
    if (lane == 0) wmax[wave] = pm;
    __syncthreads();
    if (tid == 0)
        blockmax[blockIdx.x] = umaxu(umaxu(wmax[0], wmax[1]), umaxu(wmax[2], wmax[3]));
}

__global__ __launch_bounds__(256) void k_final_fb(const ull* __restrict__ blockmax,
                                                  float* __restrict__ chars_out)
{
    __shared__ ull red[256];
    const int tid = threadIdx.x;
    ull pm = 0ull;
    for (int i = tid; i < NBH; i += 256) pm = umaxu(pm, blockmax[i]);
    red[tid] = pm;
    __syncthreads();
    for (int s = 128; s > 0; s >>= 1) {
        if (tid < s) red[tid] = umaxu(red[tid], red[tid + s]);
        __syncthreads();
    }
    if (tid == 0)
        chars_out[TLEN - 1] = (float)(0xFFFFFFFFu - (unsigned)(red[0] & 0xFFFFFFFFull));
}

// ======================================================================
extern "C" void kernel_launch(void* const* d_in, const int* in_sizes, int n_in,
                              void* d_out, int out_size, void* d_ws, size_t ws_size,
                              hipStream_t stream)
{
    const float* inputs = (const float*)d_in[0];
    const float* embed  = (const float*)d_in[1];
    const float* W_ih   = (const float*)d_in[2];
    const float* W_hh   = (const float*)d_in[3];
    const float* b_ih   = (const float*)d_in[4];
    const float* b_hh   = (const float*)d_in[5];
    const float* W_head = (const float*)d_in[6];
    const float* b_head = (const float*)d_in[7];
    const int*   startp = (const int*)d_in[9];

    float* out        = (float*)d_out;
    float* chars_out  = out;          // [2048]
    float* logits_out = out + TLEN;   // [2048 * 50257]

    char* ws = (char*)d_ws;
    const size_t off_hh = 0;
    const size_t off_c  = off_hh + (size_t)(TLEN + 1) * HID * 4;           // 8,392,704
    const size_t off_ab = off_c + (size_t)HID * 4;                         // 8,396,800
    const size_t off_bm = (off_ab + (size_t)NC * 4 + 7) & ~(size_t)7;
    const size_t off_w8 = (off_bm + (size_t)NBS * 8 + 15) & ~(size_t)15;
    const size_t need   = off_w8 + (size_t)NC * HID;

    if (ws_size >= need) {
        float* hh   = (float*)(ws + off_hh);   // hh[s] = h after s steps; hh[0]=h0
        float* c    = (float*)(ws + off_c);
        float* abuf = (float*)(ws + off_ab);
        ull*   bm   = (ull*)(ws + off_bm);
        u8*    W8   = (u8*)(ws + off_w8);

        hipLaunchKernelGGL(k_init, dim3(4), dim3(256), 0, stream, inputs, hh, c);
        hipLaunchKernelGGL(k_quant, dim3((NC * HID / 16 + 255) / 256), dim3(256), 0, stream,
                           W_head, W8);

        for (int t = 0; t < TLEN; ++t) {
            hipLaunchKernelGGL(k_lstm, dim3(256), dim3(256), 0, stream,
                               W_ih, W_hh, b_ih, b_hh, embed, W_head, b_head,
                               bm, abuf, hh + (size_t)t * HID, hh + (size_t)(t + 1) * HID,
                               c, chars_out, startp, t);
            hipLaunchKernelGGL(k_screen, dim3(NBS), dim3(256), 0, stream,
                               W8, b_head, hh + (size_t)(t + 1) * HID, abuf, bm);
        }
        hipLaunchKernelGGL(k_finalc, dim3(1), dim3(256), 0, stream,
                           hh + (size_t)TLEN * HID, bm, abuf, W_head, b_head, chars_out);
        hipLaunchKernelGGL(k_gemm, dim3((NC + GJ - 1) / GJ, TLEN / GT), dim3(256), 0, stream,
                           W_head, b_head, hh, logits_out);
    } else {
        // fallback: round-1 path (needs ~25 KB ws)
        float* h0 = (float*)(ws);
        float* h1 = (float*)(ws + 4096);
        float* c  = (float*)(ws + 8192);
        ull* blockmax = (ull*)(ws + 12288);
        hipLaunchKernelGGL(k_init_fb, dim3(7), dim3(256), 0, stream,
                           inputs, startp, h0, c, blockmax);
        for (int t = 0; t < TLEN; ++t) {
            const float* hin = (t & 1) ? h1 : h0;
            float*       hout = (t & 1) ? h0 : h1;
            hipLaunchKernelGGL(k_lstm_fb, dim3(256), dim3(256), 0, stream,
                               W_ih, W_hh, b_ih, b_hh, embed, blockmax,
                               hin, hout, c, chars_out, t);
            hipLaunchKernelGGL(k_head_fb, dim3(NBH), dim3(256), 0, stream,
                               W_head, b_head, hout,
                               logits_out + (size_t)t * NC, blockmax);
        }
        hipLaunchKernelGGL(k_final_fb, dim3(1), dim3(256), 0, stream, blockmax, chars_out);
    }
}